// Round 1
// baseline (155.829 us; speedup 1.0000x reference)
//
#include <hip/hip_runtime.h>

#define B_DIM 512
#define F_DIM 128
#define L_DIM 1024
#define K_CLS 8
#define EPS 1e-5f

// ws layout (floats): [0, K*F)   = sum
//                     [K*F,2K*F) = sumsq
//                     [2K*F,3K*F)= scale
//                     [3K*F,4K*F)= shift

// Kernel 1: per-(b,f)-row sums. One wave (64 lanes) per row of L=1024 floats.
__global__ __launch_bounds__(256) void cbn_stats(const float* __restrict__ x,
                                                 const int* __restrict__ labels,
                                                 float* __restrict__ ws) {
    const int wave = threadIdx.x >> 6;         // 0..3
    const int lane = threadIdx.x & 63;
    const int row  = blockIdx.x * 4 + wave;    // row index in [0, B*F)
    const int b = row >> 7;                    // / F_DIM
    const int f = row & (F_DIM - 1);

    const float4* x4 = reinterpret_cast<const float4*>(x) + (size_t)row * (L_DIM / 4);

    float s = 0.f, s2 = 0.f;
#pragma unroll
    for (int i = 0; i < 4; ++i) {
        float4 v = x4[i * 64 + lane];
        s  += v.x + v.y + v.z + v.w;
        s2 += v.x * v.x + v.y * v.y + v.z * v.z + v.w * v.w;
    }
    // wave64 butterfly reduce
#pragma unroll
    for (int m = 32; m >= 1; m >>= 1) {
        s  += __shfl_xor(s, m);
        s2 += __shfl_xor(s2, m);
    }
    if (lane == 0) {
        const int k = labels[b];
        atomicAdd(&ws[k * F_DIM + f], s);
        atomicAdd(&ws[K_CLS * F_DIM + k * F_DIM + f], s2);
    }
}

// Kernel 2: finalize scale/shift. One block, 1024 threads (= K*F).
__global__ __launch_bounds__(1024) void cbn_finalize(const int* __restrict__ labels,
                                                     const float* __restrict__ weight,
                                                     const float* __restrict__ bias,
                                                     float* __restrict__ ws) {
    __shared__ int cnt[K_CLS];
    const int t = threadIdx.x;
    if (t < K_CLS) cnt[t] = 0;
    __syncthreads();
    if (t < B_DIM) atomicAdd(&cnt[labels[t]], 1);
    __syncthreads();

    const int k = t >> 7;           // / F_DIM
    const float c = fmaxf((float)cnt[k] * (float)L_DIM, 1.0f);
    const float sum   = ws[t];
    const float sumsq = ws[K_CLS * F_DIM + t];
    const float mean = sum / c;
    const float var  = sumsq / c - mean * mean;
    const float inv  = rsqrtf(var + EPS);
    const float sc   = inv * weight[t];
    ws[2 * K_CLS * F_DIM + t] = sc;                 // scale[k][f]
    ws[3 * K_CLS * F_DIM + t] = bias[t] - mean * sc; // shift[k][f]
}

// Kernel 3: apply. One float4 per thread.
__global__ __launch_bounds__(256) void cbn_apply(const float* __restrict__ x,
                                                 const int* __restrict__ labels,
                                                 const float* __restrict__ ws,
                                                 float* __restrict__ y) {
    const size_t i4 = (size_t)blockIdx.x * blockDim.x + threadIdx.x; // float4 index
    const int row = (int)(i4 >> 8);          // / (L/4)
    const int b = row >> 7;
    const int f = row & (F_DIM - 1);
    const int k = labels[b];
    const float sc = ws[2 * K_CLS * F_DIM + k * F_DIM + f];
    const float sh = ws[3 * K_CLS * F_DIM + k * F_DIM + f];

    float4 v = reinterpret_cast<const float4*>(x)[i4];
    float4 o;
    o.x = v.x * sc + sh;
    o.y = v.y * sc + sh;
    o.z = v.z * sc + sh;
    o.w = v.w * sc + sh;
    reinterpret_cast<float4*>(y)[i4] = o;
}

extern "C" void kernel_launch(void* const* d_in, const int* in_sizes, int n_in,
                              void* d_out, int out_size, void* d_ws, size_t ws_size,
                              hipStream_t stream) {
    const float* x      = (const float*)d_in[0];
    const int*   labels = (const int*)d_in[1];
    const float* weight = (const float*)d_in[2];
    const float* bias   = (const float*)d_in[3];
    float* y  = (float*)d_out;
    float* ws = (float*)d_ws;

    // zero the sum/sumsq accumulators (8 KiB)
    hipMemsetAsync(ws, 0, 2 * K_CLS * F_DIM * sizeof(float), stream);

    // stats: one wave per (b,f) row; 4 waves/block
    const int nrows = B_DIM * F_DIM;
    cbn_stats<<<nrows / 4, 256, 0, stream>>>(x, labels, ws);

    cbn_finalize<<<1, 1024, 0, stream>>>(labels, weight, bias, ws);

    const size_t n4 = (size_t)B_DIM * F_DIM * L_DIM / 4;
    cbn_apply<<<(int)(n4 / 256), 256, 0, stream>>>(x, labels, ws, y);
}